// Round 2
// baseline (157.632 us; speedup 1.0000x reference)
//
#include <hip/hip_runtime.h>

constexpr int Bb = 8;
constexpr int Nn = 2048;
constexpr int Cc = 64;
constexpr int CAPS = 192;

typedef __attribute__((ext_vector_type(4))) float f32x4;
typedef __attribute__((ext_vector_type(8))) short bf16x8;

__device__ inline unsigned short f2bf(float f){
  unsigned u = __builtin_bit_cast(unsigned, f);
  unsigned r = (u + 0x7FFFu + ((u>>16)&1u)) >> 16;
  return (unsigned short)r;
}
__device__ inline float bf2f(unsigned short h){
  unsigned u = ((unsigned)h)<<16; return __builtin_bit_cast(float,u);
}

// ---------------- prep: Q,K (hi/lo bf16 split), xt = x@theta_w ----------------
// 64 rows per block; weights staged in LDS once per block.
__global__ __launch_bounds__(256) void prep_k(const float* __restrict__ x,
    const float* __restrict__ Wq, const float* __restrict__ Wk,
    const float* __restrict__ Tw, unsigned short* __restrict__ Qhi,
    unsigned short* __restrict__ Qlo, unsigned short* __restrict__ Khi,
    unsigned short* __restrict__ Klo, float* __restrict__ xt){
  __shared__ float wql[4096], wkl[4096], twl[4096];
  __shared__ float xr[4][Cc];
  int t = threadIdx.x;
  #pragma unroll
  for(int i=0;i<16;i++){
    wql[i*256+t]=Wq[i*256+t];
    wkl[i*256+t]=Wk[i*256+t];
    twl[i*256+t]=Tw[i*256+t];
  }
  long long row0 = (long long)blockIdx.x*64;
  int r = t>>6, c = t&63;
  for(int g=0; g<16; g++){
    __syncthreads();
    xr[r][c] = x[(row0+g*4)*Cc + t];
    __syncthreads();
    float q=0.f,k=0.f,th=0.f;
    #pragma unroll 8
    for(int kk=0;kk<Cc;kk++){
      float xv = xr[r][kk];
      q  += xv*wql[kk*Cc+c];
      k  += xv*wkl[kk*Cc+c];
      th += xv*twl[kk*Cc+c];
    }
    long long g2 = (row0+g*4+r)*Cc + c;
    unsigned short qh=f2bf(q); Qhi[g2]=qh; Qlo[g2]=f2bf(q-bf2f(qh));
    unsigned short kh=f2bf(k); Khi[g2]=kh; Klo[g2]=f2bf(k-bf2f(kh));
    xt[g2]=th;
  }
}

// ---------------- xsum[b][c] = sum_m x[b,m,c] ----------------
__global__ void xsum_k(const float* __restrict__ x, float* __restrict__ xsum){
  int b = blockIdx.x >> 5, g = blockIdx.x & 31;
  int c = threadIdx.x;
  float s = 0.f;
  const float* base = x + ((size_t)b*Nn + g*64)*Cc + c;
  for(int m=0;m<64;m++) s += base[m*Cc];
  atomicAdd(&xsum[b*Cc+c], s);
}

// ---------------- extract sparse structure of A ----------------
__global__ void extract_k(const float* __restrict__ A, float* __restrict__ r_,
    float* __restrict__ diagA, int* __restrict__ cnt, int* __restrict__ idx,
    float* __restrict__ val){
  int n = blockIdx.x; int l = threadIdx.x; // 64 threads = 1 wave
  const float* row = A + (size_t)n*Nn;
  float mn = 1e30f;
  for(int j=l;j<Nn;j+=64) mn = fminf(mn, row[j]);
  #pragma unroll
  for(int off=32;off>=1;off>>=1) mn = fminf(mn, __shfl_xor(mn,off));
  float thr = mn*1.3f;
  int bse=0;
  for(int j0=0;j0<Nn;j0+=64){
    float v = row[j0+l];
    bool f = v>thr;
    unsigned long long m = __ballot(f);
    int pos = __popcll(m & ((1ull<<l)-1ull));
    if(f && bse+pos<CAPS){ idx[n*CAPS+bse+pos]=j0+l; val[n*CAPS+bse+pos]=v-mn; }
    bse += __popcll(m);
  }
  if(l==0){ r_[n]=mn; diagA[n]=row[n]; cnt[n] = bse<CAPS? bse : CAPS; }
}

// ---------------- WvT[n][c] = Wv[c][n] ----------------
__global__ __launch_bounds__(256) void wvt_k(const float* __restrict__ Wv,
                                             float* __restrict__ WvT){
  __shared__ float tile[64][65];
  int n0 = blockIdx.x*64;
  int t = threadIdx.x;
  for(int i=0;i<16;i++){
    int cc = i*4 + (t>>6); int nn2 = t&63;
    tile[cc][nn2] = Wv[(size_t)cc*Nn + n0 + nn2];
  }
  __syncthreads();
  for(int i=0;i<16;i++){
    int nn2 = i*4 + (t>>6); int cc = t&63;
    WvT[(size_t)(n0+nn2)*Cc + cc] = tile[cc][nn2];
  }
}

// ---- GEMM1: E[z][j][m] = bf16(exp(Q[b,j]·K[b,m])), fused column sums -> Z ----
__device__ inline void stage_tile128(uint4* __restrict__ ldsT,
                                     const unsigned short* __restrict__ g, int t){
  #pragma unroll
  for(int i=0;i<4;i++){
    int t2 = i*256+t; int row = t2>>3, ch = t2&7;
    uint4 v = *(const uint4*)(g + row*Cc + ch*8);
    ldsT[row*8 + (ch^(row&7))] = v;   // XOR-swizzle, 16B chunks
  }
}

__global__ __launch_bounds__(256) void gemm1_k(
    const unsigned short* __restrict__ Qhi, const unsigned short* __restrict__ Qlo,
    const unsigned short* __restrict__ Khi, const unsigned short* __restrict__ Klo,
    unsigned short* __restrict__ E, float* __restrict__ Z, int b0){
  __shared__ uint4 lds[4*128*8];  // 64 KiB: Qhi,Qlo,Khi,Klo tiles 128x64 bf16
  __shared__ float colsum[128];
  int t = threadIdx.x;
  int z = blockIdx.z; int b = b0+z;
  int j0 = blockIdx.x*128, m0 = blockIdx.y*128;
  size_t bq = ((size_t)b*Nn + j0)*Cc;
  size_t bk = ((size_t)b*Nn + m0)*Cc;
  uint4* qh=lds; uint4* ql=lds+1024; uint4* kh=lds+2048; uint4* kl=lds+3072;
  stage_tile128(qh, Qhi+bq, t);
  stage_tile128(ql, Qlo+bq, t);
  stage_tile128(kh, Khi+bk, t);
  stage_tile128(kl, Klo+bk, t);
  if(t<128) colsum[t]=0.f;
  __syncthreads();
  int w=t>>6, l=t&63;
  int wm=(w>>1)*64, wn=(w&1)*64;
  f32x4 acc[4][4];
  #pragma unroll
  for(int i=0;i<4;i++)
    #pragma unroll
    for(int j=0;j<4;j++) acc[i][j]=(f32x4){0.f,0.f,0.f,0.f};
  #pragma unroll
  for(int ks=0;ks<2;ks++){
    bf16x8 ah[4],al2[4],bh[4],bl[4];
    #pragma unroll
    for(int i=0;i<4;i++){
      int R = wm+i*16+(l&15); int ch=(ks*4+(l>>4))^(R&7);
      ah[i]=*(bf16x8*)&qh[R*8+ch];
      al2[i]=*(bf16x8*)&ql[R*8+ch];
      int Rb= wn+i*16+(l&15); int cb=(ks*4+(l>>4))^(Rb&7);
      bh[i]=*(bf16x8*)&kh[Rb*8+cb];
      bl[i]=*(bf16x8*)&kl[Rb*8+cb];
    }
    #pragma unroll
    for(int i=0;i<4;i++)
      #pragma unroll
      for(int j=0;j<4;j++){
        acc[i][j]=__builtin_amdgcn_mfma_f32_16x16x32_bf16(ah[i],bh[j],acc[i][j],0,0,0);
        acc[i][j]=__builtin_amdgcn_mfma_f32_16x16x32_bf16(al2[i],bh[j],acc[i][j],0,0,0);
        acc[i][j]=__builtin_amdgcn_mfma_f32_16x16x32_bf16(ah[i],bl[j],acc[i][j],0,0,0);
      }
  }
  unsigned short* Eb = E + ((size_t)z*Nn + j0)*Nn + m0;
  float cs[4] = {0.f,0.f,0.f,0.f};
  #pragma unroll
  for(int i=0;i<4;i++){
    int row = wm+i*16+(l>>4)*4;
    #pragma unroll
    for(int j=0;j<4;j++){
      int col = wn+j*16+(l&15);
      #pragma unroll
      for(int q=0;q<4;q++){
        unsigned short h = f2bf(__expf(acc[i][j][q]));
        Eb[(size_t)(row+q)*Nn + col] = h;
        cs[j] += bf2f(h);
      }
    }
  }
  #pragma unroll
  for(int j=0;j<4;j++)
    atomicAdd(&colsum[wn + j*16 + (l&15)], cs[j]);
  __syncthreads();
  if(t<128) atomicAdd(&Z[(size_t)b*Nn + m0 + t], colsum[t]);
}

// ---------------- xzT[z][c][m] = bf16(x[b,m,c] / Z[b,m]) ----------------
__global__ __launch_bounds__(256) void xzt_k(const float* __restrict__ x,
    const float* __restrict__ Z, unsigned short* __restrict__ xzT, int b0){
  __shared__ float tile[64][65];
  int z = blockIdx.y; int b = b0+z;
  int m0 = blockIdx.x*64; int t = threadIdx.x;
  for(int i=0;i<16;i++){
    int mm = i*4 + (t>>6); int cc = t&63;
    tile[mm][cc] = x[((size_t)b*Nn + m0+mm)*Cc + cc];
  }
  __syncthreads();
  for(int i=0;i<16;i++){
    int cc = i*4 + (t>>6); int mm = t&63;
    float iz = 1.0f/Z[(size_t)b*Nn + m0+mm];
    xzT[((size_t)z*Cc + cc)*Nn + m0 + mm] = f2bf(tile[mm][cc]*iz);
  }
}

// ------- GEMM2: P[b,j,c] += sum_{m in kc} E[z,j,m] * xzT[z,c,m] (K-split) -------
__global__ __launch_bounds__(256) void gemm2_k(const unsigned short* __restrict__ E,
    const unsigned short* __restrict__ xzT, float* __restrict__ P, int b0){
  __shared__ uint4 et[128*16]; // 32 KiB
  __shared__ uint4 xb[64*16];  // 16 KiB
  int t = threadIdx.x;
  int z = blockIdx.z; int b = b0+z;
  int j0 = blockIdx.x*128;
  int kc = blockIdx.y;
  int w = t>>6, l = t&63;
  f32x4 acc[2][4];
  #pragma unroll
  for(int i=0;i<2;i++)
    #pragma unroll
    for(int j=0;j<4;j++) acc[i][j]=(f32x4){0.f,0.f,0.f,0.f};
  const unsigned short* Ebase = E + ((size_t)z*Nn + j0)*Nn;
  const unsigned short* Xbase = xzT + (size_t)z*Cc*Nn;
  for(int it=0; it<4; it++){
    int m0 = kc*512 + it*128;
    #pragma unroll
    for(int i=0;i<8;i++){
      int t2=i*256+t; int row=t2>>4, ch=t2&15;
      et[row*16 + (ch^(row&15))] = *(const uint4*)(Ebase + (size_t)row*Nn + m0 + ch*8);
    }
    #pragma unroll
    for(int i=0;i<4;i++){
      int t2=i*256+t; int row=t2>>4, ch=t2&15;
      xb[row*16 + (ch^(row&15))] = *(const uint4*)(Xbase + (size_t)row*Nn + m0 + ch*8);
    }
    __syncthreads();
    #pragma unroll
    for(int ks=0;ks<4;ks++){
      bf16x8 af[2], bfr[4];
      #pragma unroll
      for(int i=0;i<2;i++){
        int R = w*32 + i*16 + (l&15); int ch=(ks*4+(l>>4))^(R&15);
        af[i] = *(bf16x8*)&et[R*16+ch];
      }
      #pragma unroll
      for(int j=0;j<4;j++){
        int R = j*16 + (l&15); int ch=(ks*4+(l>>4))^(R&15);
        bfr[j] = *(bf16x8*)&xb[R*16+ch];
      }
      #pragma unroll
      for(int i=0;i<2;i++)
        #pragma unroll
        for(int j=0;j<4;j++)
          acc[i][j] = __builtin_amdgcn_mfma_f32_16x16x32_bf16(af[i],bfr[j],acc[i][j],0,0,0);
    }
    __syncthreads();
  }
  float* Pb = P + ((size_t)b*Nn + j0)*Cc;
  #pragma unroll
  for(int i=0;i<2;i++){
    int row = w*32 + i*16 + (l>>4)*4;
    #pragma unroll
    for(int j=0;j<4;j++){
      int col = j*16 + (l&15);
      #pragma unroll
      for(int q=0;q<4;q++)
        atomicAdd(&Pb[(size_t)(row+q)*Cc + col], acc[i][j][q]);
    }
  }
}

// ---------------- final: dy_diag + elementwise combine ----------------
__global__ __launch_bounds__(256) void final_k(const float* __restrict__ x,
    const float* __restrict__ xt, const float* __restrict__ P,
    const float* __restrict__ WvT, const float* __restrict__ xsum,
    const float* __restrict__ r_, const float* __restrict__ diagA,
    const int* __restrict__ cnt, const int* __restrict__ idx,
    const float* __restrict__ val, const float* __restrict__ tb,
    const float* __restrict__ alp, const float* __restrict__ bet,
    float* __restrict__ out){
  int t=threadIdx.x; int l=t&63;
  int bn = blockIdx.x*4 + (t>>6);
  int b = bn>>11, n = bn&2047;
  float wv = WvT[n*Cc+l];
  float tacc = r_[n]*xsum[b*Cc+l];
  int cn = cnt[n];
  const float* Pb = P + (size_t)b*Nn*Cc;
  const int* ix = idx + n*CAPS;
  const float* vl = val + n*CAPS;
  for(int k=0;k<cn;k++)
    tacc += vl[k] * Pb[(size_t)ix[k]*Cc + l];
  float d = wv*tacc;
  #pragma unroll
  for(int off=32;off>=1;off>>=1) d += __shfl_xor(d,off);
  size_t g = (size_t)bn*Cc + l;
  float o = alp[0]*diagA[n]*x[g] + bet[0]*(d*xt[g] + tb[l]);
  out[g] = fmaxf(o,0.f);
}

extern "C" void kernel_launch(void* const* d_in, const int* in_sizes, int n_in,
                              void* d_out, int out_size, void* d_ws, size_t ws_size,
                              hipStream_t stream){
  const float* x  = (const float*)d_in[0];
  const float* A  = (const float*)d_in[1];
  const float* Wq = (const float*)d_in[2];
  const float* Wk = (const float*)d_in[3];
  const float* Wv = (const float*)d_in[4];
  const float* Tw = (const float*)d_in[5];
  const float* tb = (const float*)d_in[6];
  const float* alp= (const float*)d_in[7];
  const float* bet= (const float*)d_in[8];
  float* out = (float*)d_out;

  char* base = (char*)d_ws; size_t off=0;
  auto al=[&](size_t sz)->void*{ void* q = base+off; off=(off+sz+255)&~(size_t)255; return q; };
  unsigned short* Qhi=(unsigned short*)al((size_t)Bb*Nn*Cc*2);
  unsigned short* Qlo=(unsigned short*)al((size_t)Bb*Nn*Cc*2);
  unsigned short* Khi=(unsigned short*)al((size_t)Bb*Nn*Cc*2);
  unsigned short* Klo=(unsigned short*)al((size_t)Bb*Nn*Cc*2);
  float* xt  =(float*)al((size_t)Bb*Nn*Cc*4);
  size_t zero_off = off;
  float* P   =(float*)al((size_t)Bb*Nn*Cc*4);
  float* Z   =(float*)al((size_t)Bb*Nn*4);
  float* xsum=(float*)al((size_t)Bb*Cc*4);
  size_t zero_len = off - zero_off;
  float* WvT =(float*)al((size_t)Nn*Cc*4);
  float* r_  =(float*)al((size_t)Nn*4);
  float* dgA =(float*)al((size_t)Nn*4);
  int*   cnt =(int*)al((size_t)Nn*4);
  int*   idx =(int*)al((size_t)Nn*CAPS*4);
  float* val =(float*)al((size_t)Nn*CAPS*4);
  unsigned short* xzT=(unsigned short*)al((size_t)Bb*Cc*Nn*2);
  size_t perB = (size_t)Nn*Nn*2;
  int nb = (ws_size>off)? (int)((ws_size-off)/perB) : 0;
  if(nb<1) nb=1;
  if(nb>Bb) nb=Bb;
  unsigned short* E=(unsigned short*)al((size_t)nb*perB);

  hipMemsetAsync((void*)(base+zero_off), 0, zero_len, stream);
  prep_k<<<Bb*Nn/64, 256, 0, stream>>>(x,Wq,Wk,Tw,Qhi,Qlo,Khi,Klo,xt);
  xsum_k<<<Bb*32, 64, 0, stream>>>(x, xsum);
  extract_k<<<Nn, 64, 0, stream>>>(A, r_, dgA, cnt, idx, val);
  wvt_k<<<Nn/64, 256, 0, stream>>>(Wv, WvT);
  for(int b0=0;b0<Bb;b0+=nb){
    int nbc = (Bb-b0 < nb)? (Bb-b0): nb;
    gemm1_k<<<dim3(16,16,nbc),256,0,stream>>>(Qhi,Qlo,Khi,Klo,E,Z,b0);
    xzt_k<<<dim3(32,nbc),256,0,stream>>>(x,Z,xzT,b0);
    gemm2_k<<<dim3(16,4,nbc),256,0,stream>>>(E,xzT,P,b0);
  }
  final_k<<<Bb*Nn/4,256,0,stream>>>(x,xt,P,WvT,xsum,r_,dgA,cnt,idx,val,tb,alp,bet,out);
}

// Round 3
// 128.714 us; speedup vs baseline: 1.2247x; 1.2247x over previous
//
#include <hip/hip_runtime.h>

constexpr int Bb = 8;
constexpr int Nn = 2048;
constexpr int Cc = 64;
constexpr int CAPS = 192;

typedef __attribute__((ext_vector_type(4))) float f32x4;
typedef __attribute__((ext_vector_type(8))) short bf16x8;

__device__ inline unsigned short f2bf(float f){
  unsigned u = __builtin_bit_cast(unsigned, f);
  unsigned r = (u + 0x7FFFu + ((u>>16)&1u)) >> 16;
  return (unsigned short)r;
}
__device__ inline float bf2f(unsigned short h){
  unsigned u = ((unsigned)h)<<16; return __builtin_bit_cast(float,u);
}

// ===== mega pre-kernel: prep(QK hi/lo + xt + xsum partials) | extract | WvT | zero =====
// blocks [0,256): prep, 64 rows each
// blocks [256,768): extract A sparse structure, 4 rows each (1 wave/row)
// blocks [768,800): WvT transpose
// blocks [800,865): zero P+Z region (65 x 64KB)
__global__ __launch_bounds__(256) void mega_k(
    const float* __restrict__ x, const float* __restrict__ A,
    const float* __restrict__ Wq, const float* __restrict__ Wk,
    const float* __restrict__ Tw, const float* __restrict__ Wv,
    unsigned short* __restrict__ Qhi, unsigned short* __restrict__ Qlo,
    unsigned short* __restrict__ Khi, unsigned short* __restrict__ Klo,
    float* __restrict__ xt, float* __restrict__ Xp,
    float* __restrict__ r_, float* __restrict__ diagA, int* __restrict__ cnt,
    int* __restrict__ idx, float* __restrict__ val,
    float* __restrict__ WvT, char* __restrict__ zerobase){
  __shared__ __attribute__((aligned(16))) char smem[65792];
  int blk = blockIdx.x; int t = threadIdx.x;

  if(blk < 256){
    // ---------------- prep ----------------
    float* wql = (float*)smem;           // 4096 f
    float* wkl = wql + 4096;
    float* twl = wkl + 4096;
    float (*xr)[64] = (float(*)[64])(twl + 4096); // [64][64]
    float* xsl = (float*)(xr + 64);      // 64 f
    #pragma unroll
    for(int i=0;i<4;i++){
      *(f32x4*)&wql[i*1024+t*4] = *(const f32x4*)&Wq[i*1024+t*4];
      *(f32x4*)&wkl[i*1024+t*4] = *(const f32x4*)&Wk[i*1024+t*4];
      *(f32x4*)&twl[i*1024+t*4] = *(const f32x4*)&Tw[i*1024+t*4];
    }
    if(t<64) xsl[t]=0.f;
    long long row0 = (long long)blk*64;
    int r = t>>4, q = t&15, c0 = q*4;
    #pragma unroll
    for(int i=0;i<4;i++){
      int row = i*16 + r;
      *(f32x4*)&xr[row][c0] = *(const f32x4*)&x[(row0+row)*Cc + c0];
    }
    __syncthreads();
    f32x4 aq[4], ak[4], at4[4];
    #pragma unroll
    for(int g=0;g<4;g++){ aq[g]=(f32x4){0,0,0,0}; ak[g]=(f32x4){0,0,0,0}; at4[g]=(f32x4){0,0,0,0}; }
    for(int kk=0;kk<64;kk++){
      f32x4 wq4 = *(const f32x4*)&wql[kk*64+c0];
      f32x4 wk4 = *(const f32x4*)&wkl[kk*64+c0];
      f32x4 wt4 = *(const f32x4*)&twl[kk*64+c0];
      #pragma unroll
      for(int g=0;g<4;g++){
        float xv = xr[g*16+r][kk];
        aq[g] += xv*wq4; ak[g] += xv*wk4; at4[g] += xv*wt4;
      }
    }
    float xsp[4] = {0.f,0.f,0.f,0.f};
    #pragma unroll
    for(int g=0;g<4;g++){
      #pragma unroll
      for(int d=0;d<4;d++) xsp[d] += xr[g*16+r][c0+d];
      long long g2 = (row0 + g*16 + r)*Cc + c0;
      unsigned long long hq=0,lq=0,hk=0,lk=0;
      #pragma unroll
      for(int d=0;d<4;d++){
        float v = aq[g][d];
        unsigned short h = f2bf(v); unsigned short lo2 = f2bf(v - bf2f(h));
        hq |= (unsigned long long)h << (16*d); lq |= (unsigned long long)lo2 << (16*d);
        v = ak[g][d];
        h = f2bf(v); lo2 = f2bf(v - bf2f(h));
        hk |= (unsigned long long)h << (16*d); lk |= (unsigned long long)lo2 << (16*d);
      }
      *(unsigned long long*)&Qhi[g2] = hq;
      *(unsigned long long*)&Qlo[g2] = lq;
      *(unsigned long long*)&Khi[g2] = hk;
      *(unsigned long long*)&Klo[g2] = lk;
      *(f32x4*)&xt[g2] = at4[g];
    }
    __syncthreads();
    #pragma unroll
    for(int d=0;d<4;d++) atomicAdd(&xsl[c0+d], xsp[d]);
    __syncthreads();
    if(t<64) Xp[blk*64+t] = xsl[t];
  } else if(blk < 768){
    // ---------------- extract ----------------
    int n = (blk-256)*4 + (t>>6); int l = t&63;
    const float* row = A + (size_t)n*Nn;
    float mn = 1e30f;
    for(int j=l;j<Nn;j+=64) mn = fminf(mn, row[j]);
    #pragma unroll
    for(int off=32;off>=1;off>>=1) mn = fminf(mn, __shfl_xor(mn,off));
    float thr = mn*1.3f;
    int bse=0;
    for(int j0=0;j0<Nn;j0+=64){
      float v = row[j0+l];
      bool f = v>thr;
      unsigned long long m = __ballot(f);
      int pos = __popcll(m & ((1ull<<l)-1ull));
      if(f && bse+pos<CAPS){ idx[n*CAPS+bse+pos]=j0+l; val[n*CAPS+bse+pos]=v-mn; }
      bse += __popcll(m);
    }
    if(l==0){ r_[n]=mn; diagA[n]=row[n]; cnt[n] = bse<CAPS? bse : CAPS; }
  } else if(blk < 800){
    // ---------------- WvT ----------------
    float (*tile)[65] = (float(*)[65])smem;
    int n0 = (blk-768)*64;
    for(int i=0;i<16;i++){
      int cc = i*4 + (t>>6); int nn2 = t&63;
      tile[cc][nn2] = Wv[(size_t)cc*Nn + n0 + nn2];
    }
    __syncthreads();
    for(int i=0;i<16;i++){
      int nn2 = i*4 + (t>>6); int cc = t&63;
      WvT[(size_t)(n0+nn2)*Cc + cc] = tile[cc][nn2];
    }
  } else {
    // ---------------- zero P+Z ----------------
    char* dst = zerobase + (size_t)(blk-800)*65536;
    uint4 zz = {0,0,0,0};
    #pragma unroll
    for(int i=0;i<16;i++) *(uint4*)(dst + ((size_t)i*256 + t)*16) = zz;
  }
}

// ---- GEMM1: E[b][j][m] = bf16(exp(Q[b,j]·K[b,m])), fused column sums -> Z ----
__device__ inline void stage_tile128(uint4* __restrict__ ldsT,
                                     const unsigned short* __restrict__ g, int t){
  #pragma unroll
  for(int i=0;i<4;i++){
    int t2 = i*256+t; int row = t2>>3, ch = t2&7;
    uint4 v = *(const uint4*)(g + row*Cc + ch*8);
    ldsT[row*8 + (ch^(row&7))] = v;   // XOR-swizzle, 16B chunks
  }
}

__global__ __launch_bounds__(256) void gemm1_k(
    const unsigned short* __restrict__ Qhi, const unsigned short* __restrict__ Qlo,
    const unsigned short* __restrict__ Khi, const unsigned short* __restrict__ Klo,
    unsigned short* __restrict__ E, float* __restrict__ Z){
  __shared__ uint4 lds[4*128*8];  // 64 KiB
  __shared__ float colsum[128];
  int t = threadIdx.x;
  int b = blockIdx.z;
  int j0 = blockIdx.x*128, m0 = blockIdx.y*128;
  size_t bq = ((size_t)b*Nn + j0)*Cc;
  size_t bk = ((size_t)b*Nn + m0)*Cc;
  uint4* qh=lds; uint4* ql=lds+1024; uint4* kh=lds+2048; uint4* kl=lds+3072;
  stage_tile128(qh, Qhi+bq, t);
  stage_tile128(ql, Qlo+bq, t);
  stage_tile128(kh, Khi+bk, t);
  stage_tile128(kl, Klo+bk, t);
  if(t<128) colsum[t]=0.f;
  __syncthreads();
  int w=t>>6, l=t&63;
  int wm=(w>>1)*64, wn=(w&1)*64;
  f32x4 acc[4][4];
  #pragma unroll
  for(int i=0;i<4;i++)
    #pragma unroll
    for(int j=0;j<4;j++) acc[i][j]=(f32x4){0.f,0.f,0.f,0.f};
  #pragma unroll
  for(int ks=0;ks<2;ks++){
    bf16x8 ah[4],al2[4],bh[4],bl[4];
    #pragma unroll
    for(int i=0;i<4;i++){
      int R = wm+i*16+(l&15); int ch=(ks*4+(l>>4))^(R&7);
      ah[i]=*(bf16x8*)&qh[R*8+ch];
      al2[i]=*(bf16x8*)&ql[R*8+ch];
      int Rb= wn+i*16+(l&15); int cb=(ks*4+(l>>4))^(Rb&7);
      bh[i]=*(bf16x8*)&kh[Rb*8+cb];
      bl[i]=*(bf16x8*)&kl[Rb*8+cb];
    }
    #pragma unroll
    for(int i=0;i<4;i++)
      #pragma unroll
      for(int j=0;j<4;j++){
        acc[i][j]=__builtin_amdgcn_mfma_f32_16x16x32_bf16(ah[i],bh[j],acc[i][j],0,0,0);
        acc[i][j]=__builtin_amdgcn_mfma_f32_16x16x32_bf16(al2[i],bh[j],acc[i][j],0,0,0);
        acc[i][j]=__builtin_amdgcn_mfma_f32_16x16x32_bf16(ah[i],bl[j],acc[i][j],0,0,0);
      }
  }
  unsigned short* Eb = E + ((size_t)b*Nn + j0)*Nn + m0;
  float cs[4] = {0.f,0.f,0.f,0.f};
  #pragma unroll
  for(int i=0;i<4;i++){
    int row = wm+i*16+(l>>4)*4;
    #pragma unroll
    for(int j=0;j<4;j++){
      int col = wn+j*16+(l&15);
      #pragma unroll
      for(int q=0;q<4;q++){
        unsigned short h = f2bf(__expf(acc[i][j][q]));
        Eb[(size_t)(row+q)*Nn + col] = h;
        cs[j] += bf2f(h);
      }
    }
  }
  #pragma unroll
  for(int j=0;j<4;j++)
    atomicAdd(&colsum[wn + j*16 + (l&15)], cs[j]);
  __syncthreads();
  if(t<128) atomicAdd(&Z[(size_t)b*Nn + m0 + t], colsum[t]);
}

// ---------------- xzT[b][c][m] = bf16(x[b,m,c] / Z[b,m]) ----------------
__global__ __launch_bounds__(256) void xzt_k(const float* __restrict__ x,
    const float* __restrict__ Z, unsigned short* __restrict__ xzT){
  __shared__ float tile[64][65];
  int b = blockIdx.y;
  int m0 = blockIdx.x*64; int t = threadIdx.x;
  for(int i=0;i<16;i++){
    int mm = i*4 + (t>>6); int cc = t&63;
    tile[mm][cc] = x[((size_t)b*Nn + m0+mm)*Cc + cc];
  }
  __syncthreads();
  for(int i=0;i<16;i++){
    int cc = i*4 + (t>>6); int mm = t&63;
    float iz = 1.0f/Z[(size_t)b*Nn + m0+mm];
    xzT[((size_t)b*Cc + cc)*Nn + m0 + mm] = f2bf(tile[mm][cc]*iz);
  }
}

// ------- GEMM2: P[b,j,c] += sum_{m in kc} E[b,j,m] * xzT[b,c,m] (K-split) -------
__global__ __launch_bounds__(256) void gemm2_k(const unsigned short* __restrict__ E,
    const unsigned short* __restrict__ xzT, float* __restrict__ P){
  __shared__ uint4 et[128*16]; // 32 KiB
  __shared__ uint4 xb[64*16];  // 16 KiB
  int t = threadIdx.x;
  int b = blockIdx.z;
  int j0 = blockIdx.x*128;
  int kc = blockIdx.y;
  int w = t>>6, l = t&63;
  f32x4 acc[2][4];
  #pragma unroll
  for(int i=0;i<2;i++)
    #pragma unroll
    for(int j=0;j<4;j++) acc[i][j]=(f32x4){0.f,0.f,0.f,0.f};
  const unsigned short* Ebase = E + ((size_t)b*Nn + j0)*Nn;
  const unsigned short* Xbase = xzT + (size_t)b*Cc*Nn;
  for(int it=0; it<4; it++){
    int m0 = kc*512 + it*128;
    #pragma unroll
    for(int i=0;i<8;i++){
      int t2=i*256+t; int row=t2>>4, ch=t2&15;
      et[row*16 + (ch^(row&15))] = *(const uint4*)(Ebase + (size_t)row*Nn + m0 + ch*8);
    }
    #pragma unroll
    for(int i=0;i<4;i++){
      int t2=i*256+t; int row=t2>>4, ch=t2&15;
      xb[row*16 + (ch^(row&15))] = *(const uint4*)(Xbase + (size_t)row*Nn + m0 + ch*8);
    }
    __syncthreads();
    #pragma unroll
    for(int ks=0;ks<4;ks++){
      bf16x8 af[2], bfr[4];
      #pragma unroll
      for(int i=0;i<2;i++){
        int R = w*32 + i*16 + (l&15); int ch=(ks*4+(l>>4))^(R&15);
        af[i] = *(bf16x8*)&et[R*16+ch];
      }
      #pragma unroll
      for(int j=0;j<4;j++){
        int R = j*16 + (l&15); int ch=(ks*4+(l>>4))^(R&15);
        bfr[j] = *(bf16x8*)&xb[R*16+ch];
      }
      #pragma unroll
      for(int i=0;i<2;i++)
        #pragma unroll
        for(int j=0;j<4;j++)
          acc[i][j] = __builtin_amdgcn_mfma_f32_16x16x32_bf16(af[i],bfr[j],acc[i][j],0,0,0);
    }
    __syncthreads();
  }
  float* Pb = P + ((size_t)b*Nn + j0)*Cc;
  #pragma unroll
  for(int i=0;i<2;i++){
    int row = w*32 + i*16 + (l>>4)*4;
    #pragma unroll
    for(int j=0;j<4;j++){
      int col = j*16 + (l&15);
      #pragma unroll
      for(int q=0;q<4;q++)
        atomicAdd(&Pb[(size_t)(row+q)*Cc + col], acc[i][j][q]);
    }
  }
}

// ---------------- final: dy_diag + elementwise combine ----------------
__global__ __launch_bounds__(256) void final_k(const float* __restrict__ x,
    const float* __restrict__ xt, const float* __restrict__ P,
    const float* __restrict__ WvT, const float* __restrict__ Xp,
    const float* __restrict__ r_, const float* __restrict__ diagA,
    const int* __restrict__ cnt, const int* __restrict__ idx,
    const float* __restrict__ val, const float* __restrict__ tb,
    const float* __restrict__ alp, const float* __restrict__ bet,
    float* __restrict__ out){
  int t=threadIdx.x; int l=t&63;
  int bn = blockIdx.x*4 + (t>>6);
  int b = bn>>11, n = bn&2047;
  float wv = WvT[n*Cc+l];
  float xs = 0.f;
  const float* xpb = Xp + (size_t)b*32*Cc;
  #pragma unroll 8
  for(int p=0;p<32;p++) xs += xpb[p*Cc + l];
  float tacc = r_[n]*xs;
  int cn = cnt[n];
  const float* Pb = P + (size_t)b*Nn*Cc;
  const int* ix = idx + n*CAPS;
  const float* vl = val + n*CAPS;
  for(int k=0;k<cn;k++)
    tacc += vl[k] * Pb[(size_t)ix[k]*Cc + l];
  float d = wv*tacc;
  #pragma unroll
  for(int off=32;off>=1;off>>=1) d += __shfl_xor(d,off);
  size_t g = (size_t)bn*Cc + l;
  float o = alp[0]*diagA[n]*x[g] + bet[0]*(d*xt[g] + tb[l]);
  out[g] = fmaxf(o,0.f);
}

extern "C" void kernel_launch(void* const* d_in, const int* in_sizes, int n_in,
                              void* d_out, int out_size, void* d_ws, size_t ws_size,
                              hipStream_t stream){
  const float* x  = (const float*)d_in[0];
  const float* A  = (const float*)d_in[1];
  const float* Wq = (const float*)d_in[2];
  const float* Wk = (const float*)d_in[3];
  const float* Wv = (const float*)d_in[4];
  const float* Tw = (const float*)d_in[5];
  const float* tb = (const float*)d_in[6];
  const float* alp= (const float*)d_in[7];
  const float* bet= (const float*)d_in[8];
  float* out = (float*)d_out;

  char* base = (char*)d_ws; size_t off=0;
  auto al=[&](size_t sz)->void*{ void* q = base+off; off=(off+sz+255)&~(size_t)255; return q; };
  unsigned short* Qhi=(unsigned short*)al((size_t)Bb*Nn*Cc*2);
  unsigned short* Qlo=(unsigned short*)al((size_t)Bb*Nn*Cc*2);
  unsigned short* Khi=(unsigned short*)al((size_t)Bb*Nn*Cc*2);
  unsigned short* Klo=(unsigned short*)al((size_t)Bb*Nn*Cc*2);
  float* xt  =(float*)al((size_t)Bb*Nn*Cc*4);
  float* P   =(float*)al((size_t)Bb*Nn*Cc*4);   // zeroed by mega_k
  float* Z   =(float*)al((size_t)Bb*Nn*4);      // zeroed by mega_k (contiguous after P)
  float* Xp  =(float*)al((size_t)256*Cc*4);
  float* WvT =(float*)al((size_t)Nn*Cc*4);
  float* r_  =(float*)al((size_t)Nn*4);
  float* dgA =(float*)al((size_t)Nn*4);
  int*   cnt =(int*)al((size_t)Nn*4);
  int*   idx =(int*)al((size_t)Nn*CAPS*4);
  float* val =(float*)al((size_t)Nn*CAPS*4);
  unsigned short* xzT=(unsigned short*)al((size_t)Bb*Cc*Nn*2);
  unsigned short* E  =(unsigned short*)al((size_t)Bb*Nn*Nn*2);
  (void)ws_size;

  mega_k<<<865, 256, 0, stream>>>(x, A, Wq, Wk, Tw, Wv,
      Qhi, Qlo, Khi, Klo, xt, Xp, r_, dgA, cnt, idx, val, WvT, (char*)P);
  gemm1_k<<<dim3(16,16,Bb), 256, 0, stream>>>(Qhi,Qlo,Khi,Klo,E,Z);
  xzt_k<<<dim3(32,Bb), 256, 0, stream>>>(x,Z,xzT);
  gemm2_k<<<dim3(16,4,Bb), 256, 0, stream>>>(E,xzT,P);
  final_k<<<Bb*Nn/4, 256, 0, stream>>>(x,xt,P,WvT,Xp,r_,dgA,cnt,idx,val,tb,alp,bet,out);
}